// Round 6
// baseline (51.299 us; speedup 1.0000x reference)
//
#include <hip/hip_runtime.h>
#include <math.h>

// Problem constants (match setup_inputs)
#define B_ 4
#define N_ 128
#define D_ 160
#define H_ 192
#define W_ 160

// Native clang vector type for 16B stores.
typedef float floatx4 __attribute__((ext_vector_type(4)));

#define F_PER_ROW ((W_ * 3) / 4)              /* 120 float4s per row        */
#define F4_TOTAL (B_ * D_ * H_ * F_PER_ROW)   /* 14,745,600                 */
#define NBLOCKS 1800                          /* 8192 f4 per block exactly  */
#define F4_PER_BLOCK (F4_TOTAL / NBLOCKS)     /* 8192 = 32 per thread       */
#define BLOCKS_PER_BATCH (NBLOCKS / B_)       /* 450 -> b is block-uniform  */

// ---------------------------------------------------------------------------
// SINGLE fused kernel.
//
// Rationale: the two-kernel version paid ~5-7 us for the rigid dispatch
// (1 block on a 256-CU chip + graph serialization). The rigid solve is tiny
// (~530 VALU instr), so every WAVE recomputes its batch's theta redundantly:
//   - __shfl_xor butterfly leaves the full sum in EVERY lane -> no LDS,
//     no __syncthreads, no inter-kernel dependency.
//   - b = blockIdx.x / 450 is block-uniform (8192 f4/block, 450 blocks/batch).
//   - prologue cost ~0.5 us, paid concurrently by all resident waves, then
//     hidden under 33+ us of write-streaming.
//
// Rigid math (p1 = points_f, p2 = points_m, w normalized):
//   c1 = sum w*p1 ; c2 = sum w*p2
//   H[i][j] = sum_n w^2 (p1_i - c1_i)(p2_j - c2_j)
//   R_init = V U^T = Q^T (Q = orthogonal polar factor of H), via det-scaled
//   Newton X <- 0.5*(mu*X + C/(mu*det)), 8 f32 iters (fixed point is exact;
//   f32 stalls ~1e-6, threshold 3.7e-2).
//   R = diag(1,1,sign(det(R_init))) * R_init ; T = c2 - R c1
//
// Grid math: out[b,d,h,w,i] = R[i].(x,y,z) + T[i],
//   x=(2w+1)/W-1, y=(2h+1)/H-1, z=(2d+1)/D-1.
// One thread = 32 float4s at stride 256: every store instruction is
// 64 lanes x 16 B = 1 KiB contiguous (plain stores; nt regressed in R4).
// ---------------------------------------------------------------------------
__global__ __launch_bounds__(256) void fused_kernel(const float* __restrict__ pm,
                                                    const float* __restrict__ pf,
                                                    const float* __restrict__ wt,
                                                    floatx4* __restrict__ out) {
  const int tid = threadIdx.x;
  const int blk = blockIdx.x;
  const int b = blk / BLOCKS_PER_BATCH; // block-uniform -> scalar
  const int lane = tid & 63;

  // ===== per-wave redundant rigid solve for batch b =====
  const int base = b * N_;
  const float wA = wt[base + lane], wB = wt[base + lane + 64];
  float fA[3], fB[3], mA[3], mB[3];
#pragma unroll
  for (int c = 0; c < 3; ++c) {
    fA[c] = pf[(base + lane) * 3 + c];
    fB[c] = pf[(base + lane + 64) * 3 + c];
    mA[c] = pm[(base + lane) * 3 + c];
    mB[c] = pm[(base + lane + 64) * 3 + c];
  }

  // centroids: 6 butterfly reductions (result lands in ALL lanes)
  float sums[6];
#pragma unroll
  for (int c = 0; c < 3; ++c) {
    sums[c]     = wA * fA[c] + wB * fB[c];
    sums[3 + c] = wA * mA[c] + wB * mB[c];
  }
#pragma unroll
  for (int k = 0; k < 6; ++k) {
    float v = sums[k];
#pragma unroll
    for (int o = 1; o < 64; o <<= 1) v += __shfl_xor(v, o, 64);
    sums[k] = v;
  }

  // cross-covariance H: 9 butterfly reductions
  float q1A[3], q1B[3], q2A[3], q2B[3];
#pragma unroll
  for (int c = 0; c < 3; ++c) {
    q1A[c] = (fA[c] - sums[c]) * wA;     q1B[c] = (fB[c] - sums[c]) * wB;
    q2A[c] = (mA[c] - sums[3 + c]) * wA; q2B[c] = (mB[c] - sums[3 + c]) * wB;
  }
  float X[3][3];
#pragma unroll
  for (int i = 0; i < 3; ++i)
#pragma unroll
    for (int j = 0; j < 3; ++j)
      X[i][j] = q1A[i] * q2A[j] + q1B[i] * q2B[j];
#pragma unroll
  for (int i = 0; i < 3; ++i)
#pragma unroll
    for (int j = 0; j < 3; ++j) {
      float v = X[i][j];
#pragma unroll
      for (int o = 1; o < 64; o <<= 1) v += __shfl_xor(v, o, 64);
      X[i][j] = v;
    }

  // polar solve (every lane redundantly; values are wave-uniform)
  {
    float fr = 0.0f;
#pragma unroll
    for (int i = 0; i < 3; ++i)
#pragma unroll
      for (int j = 0; j < 3; ++j) fr = fmaf(X[i][j], X[i][j], fr);
    fr = sqrtf(fr);
    if (fr < 1e-30f) fr = 1.0f;
    const float ifr = 1.0f / fr;
#pragma unroll
    for (int i = 0; i < 3; ++i)
#pragma unroll
      for (int j = 0; j < 3; ++j) X[i][j] *= ifr;
  }

  for (int it = 0; it < 8; ++it) {
    float C[3][3];
    C[0][0] =  X[1][1] * X[2][2] - X[1][2] * X[2][1];
    C[0][1] = -(X[1][0] * X[2][2] - X[1][2] * X[2][0]);
    C[0][2] =  X[1][0] * X[2][1] - X[1][1] * X[2][0];
    C[1][0] = -(X[0][1] * X[2][2] - X[0][2] * X[2][1]);
    C[1][1] =  X[0][0] * X[2][2] - X[0][2] * X[2][0];
    C[1][2] = -(X[0][0] * X[2][1] - X[0][1] * X[2][0]);
    C[2][0] =  X[0][1] * X[1][2] - X[0][2] * X[1][1];
    C[2][1] = -(X[0][0] * X[1][2] - X[0][2] * X[1][0]);
    C[2][2] =  X[0][0] * X[1][1] - X[0][1] * X[1][0];
    float det = X[0][0] * C[0][0] + X[0][1] * C[0][1] + X[0][2] * C[0][2];
    // mu ~= |det|^(-1/3): precision affects only convergence rate.
    float ad = fabsf(det);
    float mu = (ad > 1e-30f && ad < 1e30f)
                   ? exp2f(log2f(ad) * (-1.0f / 3.0f)) : 1.0f;
    float inv = 1.0f / (mu * det);
#pragma unroll
    for (int i = 0; i < 3; ++i)
#pragma unroll
      for (int j = 0; j < 3; ++j)
        X[i][j] = 0.5f * fmaf(mu, X[i][j], C[i][j] * inv);
  }

  // R_init = X^T; flip 3rd row by sign(det); T = c2 - R c1
  float R[3][3];
#pragma unroll
  for (int i = 0; i < 3; ++i)
#pragma unroll
    for (int j = 0; j < 3; ++j) R[i][j] = X[j][i];
  {
    float det = R[0][0] * (R[1][1] * R[2][2] - R[1][2] * R[2][1])
              - R[0][1] * (R[1][0] * R[2][2] - R[1][2] * R[2][0])
              + R[0][2] * (R[1][0] * R[2][1] - R[1][1] * R[2][0]);
    float s = (det < 0.0f) ? -1.0f : 1.0f;
    R[2][0] *= s; R[2][1] *= s; R[2][2] *= s;
  }
  const float t0 = sums[3] - (R[0][0] * sums[0] + R[0][1] * sums[1] + R[0][2] * sums[2]);
  const float t1 = sums[4] - (R[1][0] * sums[0] + R[1][1] * sums[1] + R[1][2] * sums[2]);
  const float t2 = sums[5] - (R[2][0] * sums[0] + R[2][1] * sums[1] + R[2][2] * sums[2]);
  const float r00 = R[0][0], r01 = R[0][1], r02 = R[0][2];
  const float r10 = R[1][0], r11 = R[1][1], r12 = R[1][2];
  const float r20 = R[2][0], r21 = R[2][1], r22 = R[2][2];
  const float dx = 2.0f / (float)W_;

  // ===== write-streaming: 32 float4s per thread, stride 256 =====
  int f = blk * F4_PER_BLOCK + tid;
#pragma unroll 4
  for (int k = 0; k < 32; ++k, f += 256) {
    const int row = f / F_PER_ROW;
    const int lf4 = f - row * F_PER_ROW;
    const int h = row % H_;
    const int d = (row / H_) % D_;

    const int lf = lf4 * 4;        // float offset within row, 0..476
    const int w0 = lf / 3;         // first voxel covered
    const int phase = lf - 3 * w0; // 0,1,2

    const float y = (2.0f * (float)h + 1.0f) * (1.0f / (float)H_) - 1.0f;
    const float z = (2.0f * (float)d + 1.0f) * (1.0f / (float)D_) - 1.0f;
    const float x0 = (2.0f * (float)w0 + 1.0f) * (1.0f / (float)W_) - 1.0f;

    const float A0 = fmaf(r00, x0, fmaf(r01, y, fmaf(r02, z, t0)));
    const float A1 = fmaf(r10, x0, fmaf(r11, y, fmaf(r12, z, t1)));
    const float A2 = fmaf(r20, x0, fmaf(r21, y, fmaf(r22, z, t2)));
    const float B0 = fmaf(r00, dx, A0);
    const float B1 = fmaf(r10, dx, A1);
    const float B2 = fmaf(r20, dx, A2);

    floatx4 o;
    o.x = (phase == 0) ? A0 : ((phase == 1) ? A1 : A2);
    o.y = (phase == 0) ? A1 : ((phase == 1) ? A2 : B0);
    o.z = (phase == 0) ? A2 : ((phase == 1) ? B0 : B1);
    o.w = (phase == 0) ? B0 : ((phase == 1) ? B1 : B2);

    out[f] = o;
  }
}

extern "C" void kernel_launch(void* const* d_in, const int* in_sizes, int n_in,
                              void* d_out, int out_size, void* d_ws, size_t ws_size,
                              hipStream_t stream) {
  const float* pm = (const float*)d_in[0]; // points_m [B,N,3]
  const float* pf = (const float*)d_in[1]; // points_f [B,N,3]
  const float* wt = (const float*)d_in[2]; // weights  [B,1,N]
  floatx4* out = (floatx4*)d_out;          // [B,D,H,W,3] f32 as float4s

  fused_kernel<<<NBLOCKS, 256, 0, stream>>>(pm, pf, wt, out);
}

// Round 7
// 50.099 us; speedup vs baseline: 1.0240x; 1.0240x over previous
//
#include <hip/hip_runtime.h>
#include <math.h>

// Problem constants (match setup_inputs)
#define B_ 4
#define N_ 128
#define D_ 160
#define H_ 192
#define W_ 160

// Native clang vector type for 16B stores.
typedef float floatx4 __attribute__((ext_vector_type(4)));

#define F_PER_ROW ((W_ * 3) / 4)              /* 120 float4s per row        */
#define F4_TOTAL (B_ * D_ * H_ * F_PER_ROW)   /* 14,745,600                 */
#define NBLOCKS 2304                          /* 9*256: ZERO tail, 9/CU     */
#define F4_PER_BLOCK (F4_TOTAL / NBLOCKS)     /* 6400 = 25 per thread       */
#define BLOCKS_PER_BATCH (NBLOCKS / B_)       /* 576 -> b is block-uniform  */

// ---------------------------------------------------------------------------
// SINGLE fused kernel (R6 structure; ONLY the grid geometry changed).
//
// R6 lesson: 1800 blocks = 7*256 + 8 -> one extra full ~6.4us quantum on 8
// CUs while 248 idle (load-imbalance tail). 2304 = 9*256 gives exactly 9
// equal blocks per CU, zero tail.
//
// Every wave redundantly computes its batch's theta (butterfly reductions
// leave the result in all lanes; no LDS, no barriers, no 2nd kernel):
//   c1 = sum w*p1 ; c2 = sum w*p2          (p1=points_f, p2=points_m)
//   H[i][j] = sum_n w^2 (p1_i-c1_i)(p2_j-c2_j)
//   R_init = Q^T via det-scaled Newton X <- 0.5*(mu*X + C/(mu*det)), 8 f32
//   iters (fixed point exact; f32 stalls ~1e-6, threshold 3.7e-2).
//   R = diag(1,1,sign(det)) * R_init ; T = c2 - R c1
//
// Grid: out[b,d,h,w,i] = R[i].(x,y,z) + T[i], x=(2w+1)/W-1 etc.
// One thread = 25 float4s at stride 256: every store instruction is
// 64 lanes x 16 B = 1 KiB contiguous (plain stores; nt regressed in R4).
// ---------------------------------------------------------------------------
__global__ __launch_bounds__(256) void fused_kernel(const float* __restrict__ pm,
                                                    const float* __restrict__ pf,
                                                    const float* __restrict__ wt,
                                                    floatx4* __restrict__ out) {
  const int tid = threadIdx.x;
  const int blk = blockIdx.x;
  const int b = blk / BLOCKS_PER_BATCH; // block-uniform -> scalar
  const int lane = tid & 63;

  // ===== per-wave redundant rigid solve for batch b =====
  const int base = b * N_;
  const float wA = wt[base + lane], wB = wt[base + lane + 64];
  float fA[3], fB[3], mA[3], mB[3];
#pragma unroll
  for (int c = 0; c < 3; ++c) {
    fA[c] = pf[(base + lane) * 3 + c];
    fB[c] = pf[(base + lane + 64) * 3 + c];
    mA[c] = pm[(base + lane) * 3 + c];
    mB[c] = pm[(base + lane + 64) * 3 + c];
  }

  // centroids: 6 butterfly reductions (result lands in ALL lanes)
  float sums[6];
#pragma unroll
  for (int c = 0; c < 3; ++c) {
    sums[c]     = wA * fA[c] + wB * fB[c];
    sums[3 + c] = wA * mA[c] + wB * mB[c];
  }
#pragma unroll
  for (int k = 0; k < 6; ++k) {
    float v = sums[k];
#pragma unroll
    for (int o = 1; o < 64; o <<= 1) v += __shfl_xor(v, o, 64);
    sums[k] = v;
  }

  // cross-covariance H: 9 butterfly reductions
  float q1A[3], q1B[3], q2A[3], q2B[3];
#pragma unroll
  for (int c = 0; c < 3; ++c) {
    q1A[c] = (fA[c] - sums[c]) * wA;     q1B[c] = (fB[c] - sums[c]) * wB;
    q2A[c] = (mA[c] - sums[3 + c]) * wA; q2B[c] = (mB[c] - sums[3 + c]) * wB;
  }
  float X[3][3];
#pragma unroll
  for (int i = 0; i < 3; ++i)
#pragma unroll
    for (int j = 0; j < 3; ++j)
      X[i][j] = q1A[i] * q2A[j] + q1B[i] * q2B[j];
#pragma unroll
  for (int i = 0; i < 3; ++i)
#pragma unroll
    for (int j = 0; j < 3; ++j) {
      float v = X[i][j];
#pragma unroll
      for (int o = 1; o < 64; o <<= 1) v += __shfl_xor(v, o, 64);
      X[i][j] = v;
    }

  // polar solve (every lane redundantly; values are wave-uniform)
  {
    float fr = 0.0f;
#pragma unroll
    for (int i = 0; i < 3; ++i)
#pragma unroll
      for (int j = 0; j < 3; ++j) fr = fmaf(X[i][j], X[i][j], fr);
    fr = sqrtf(fr);
    if (fr < 1e-30f) fr = 1.0f;
    const float ifr = 1.0f / fr;
#pragma unroll
    for (int i = 0; i < 3; ++i)
#pragma unroll
      for (int j = 0; j < 3; ++j) X[i][j] *= ifr;
  }

  for (int it = 0; it < 8; ++it) {
    float C[3][3];
    C[0][0] =  X[1][1] * X[2][2] - X[1][2] * X[2][1];
    C[0][1] = -(X[1][0] * X[2][2] - X[1][2] * X[2][0]);
    C[0][2] =  X[1][0] * X[2][1] - X[1][1] * X[2][0];
    C[1][0] = -(X[0][1] * X[2][2] - X[0][2] * X[2][1]);
    C[1][1] =  X[0][0] * X[2][2] - X[0][2] * X[2][0];
    C[1][2] = -(X[0][0] * X[2][1] - X[0][1] * X[2][0]);
    C[2][0] =  X[0][1] * X[1][2] - X[0][2] * X[1][1];
    C[2][1] = -(X[0][0] * X[1][2] - X[0][2] * X[1][0]);
    C[2][2] =  X[0][0] * X[1][1] - X[0][1] * X[1][0];
    float det = X[0][0] * C[0][0] + X[0][1] * C[0][1] + X[0][2] * C[0][2];
    // mu ~= |det|^(-1/3): precision affects only convergence rate.
    float ad = fabsf(det);
    float mu = (ad > 1e-30f && ad < 1e30f)
                   ? exp2f(log2f(ad) * (-1.0f / 3.0f)) : 1.0f;
    float inv = 1.0f / (mu * det);
#pragma unroll
    for (int i = 0; i < 3; ++i)
#pragma unroll
      for (int j = 0; j < 3; ++j)
        X[i][j] = 0.5f * fmaf(mu, X[i][j], C[i][j] * inv);
  }

  // R_init = X^T; flip 3rd row by sign(det); T = c2 - R c1
  float R[3][3];
#pragma unroll
  for (int i = 0; i < 3; ++i)
#pragma unroll
    for (int j = 0; j < 3; ++j) R[i][j] = X[j][i];
  {
    float det = R[0][0] * (R[1][1] * R[2][2] - R[1][2] * R[2][1])
              - R[0][1] * (R[1][0] * R[2][2] - R[1][2] * R[2][0])
              + R[0][2] * (R[1][0] * R[2][1] - R[1][1] * R[2][0]);
    float s = (det < 0.0f) ? -1.0f : 1.0f;
    R[2][0] *= s; R[2][1] *= s; R[2][2] *= s;
  }
  const float t0 = sums[3] - (R[0][0] * sums[0] + R[0][1] * sums[1] + R[0][2] * sums[2]);
  const float t1 = sums[4] - (R[1][0] * sums[0] + R[1][1] * sums[1] + R[1][2] * sums[2]);
  const float t2 = sums[5] - (R[2][0] * sums[0] + R[2][1] * sums[1] + R[2][2] * sums[2]);
  const float r00 = R[0][0], r01 = R[0][1], r02 = R[0][2];
  const float r10 = R[1][0], r11 = R[1][1], r12 = R[1][2];
  const float r20 = R[2][0], r21 = R[2][1], r22 = R[2][2];
  const float dx = 2.0f / (float)W_;

  // ===== write-streaming: 25 float4s per thread, stride 256 =====
  int f = blk * F4_PER_BLOCK + tid;
#pragma unroll 5
  for (int k = 0; k < 25; ++k, f += 256) {
    const int row = f / F_PER_ROW;
    const int lf4 = f - row * F_PER_ROW;
    const int h = row % H_;
    const int d = (row / H_) % D_;

    const int lf = lf4 * 4;        // float offset within row, 0..476
    const int w0 = lf / 3;         // first voxel covered
    const int phase = lf - 3 * w0; // 0,1,2

    const float y = (2.0f * (float)h + 1.0f) * (1.0f / (float)H_) - 1.0f;
    const float z = (2.0f * (float)d + 1.0f) * (1.0f / (float)D_) - 1.0f;
    const float x0 = (2.0f * (float)w0 + 1.0f) * (1.0f / (float)W_) - 1.0f;

    const float A0 = fmaf(r00, x0, fmaf(r01, y, fmaf(r02, z, t0)));
    const float A1 = fmaf(r10, x0, fmaf(r11, y, fmaf(r12, z, t1)));
    const float A2 = fmaf(r20, x0, fmaf(r21, y, fmaf(r22, z, t2)));
    const float B0 = fmaf(r00, dx, A0);
    const float B1 = fmaf(r10, dx, A1);
    const float B2 = fmaf(r20, dx, A2);

    floatx4 o;
    o.x = (phase == 0) ? A0 : ((phase == 1) ? A1 : A2);
    o.y = (phase == 0) ? A1 : ((phase == 1) ? A2 : B0);
    o.z = (phase == 0) ? A2 : ((phase == 1) ? B0 : B1);
    o.w = (phase == 0) ? B0 : ((phase == 1) ? B1 : B2);

    out[f] = o;
  }
}

extern "C" void kernel_launch(void* const* d_in, const int* in_sizes, int n_in,
                              void* d_out, int out_size, void* d_ws, size_t ws_size,
                              hipStream_t stream) {
  const float* pm = (const float*)d_in[0]; // points_m [B,N,3]
  const float* pf = (const float*)d_in[1]; // points_f [B,N,3]
  const float* wt = (const float*)d_in[2]; // weights  [B,1,N]
  floatx4* out = (floatx4*)d_out;          // [B,D,H,W,3] f32 as float4s

  fused_kernel<<<NBLOCKS, 256, 0, stream>>>(pm, pf, wt, out);
}

// Round 8
// 46.091 us; speedup vs baseline: 1.1130x; 1.0870x over previous
//
#include <hip/hip_runtime.h>
#include <math.h>

// Problem constants (match setup_inputs)
#define B_ 4
#define N_ 128
#define D_ 160
#define H_ 192
#define W_ 160

// Native clang vector type for 16B stores.
typedef float floatx4 __attribute__((ext_vector_type(4)));

#define F_PER_ROW ((W_ * 3) / 4)              /* 120 float4s per row        */
#define F4_TOTAL (B_ * D_ * H_ * F_PER_ROW)   /* 14,745,600                 */
#define NBLOCKS 2304                          /* 9*256: zero tail, 9/CU     */
#define F4_PER_BLOCK (F4_TOTAL / NBLOCKS)     /* 6400 = 25 per thread       */
#define BLOCKS_PER_BATCH (NBLOCKS / B_)       /* 576 -> b is block-uniform  */

// ---------------------------------------------------------------------------
// SINGLE fused kernel. R7 lesson: running the rigid solve on EVERY wave cost
// ~5.5us -- 36 waves/CU hammer the LDS pipe (90 shfl = ds_bpermute each) and
// VALU with ~700 redundant instructions at t=0, before any store can issue.
// Fix: ONLY WAVE 0 of each block solves (9 wave0s/CU), publishes theta via
// 12 floats of LDS, one __syncthreads, then all 4 waves stream. Waves 1-3
// wait idle at the barrier instead of contending for issue slots.
//
// Rigid math (p1=points_f, p2=points_m, w normalized):
//   c1 = sum w*p1 ; c2 = sum w*p2
//   H[i][j] = sum_n w^2 (p1_i-c1_i)(p2_j-c2_j)
//   R_init = V U^T = Q^T (orth. polar factor of H) via det-scaled Newton
//   X <- 0.5*(mu*X + C/(mu*det)), 8 f32 iters (fixed point exact; f32
//   stalls ~1e-6, threshold 3.7e-2).
//   R = diag(1,1,sign(det)) * R_init ; T = c2 - R c1
//
// Grid: out[b,d,h,w,i] = R[i].(x,y,z)+T[i], x=(2w+1)/W-1, y=(2h+1)/H-1,
// z=(2d+1)/D-1. One thread = 25 float4s at stride 256: every store
// instruction is 64 lanes x 16 B = 1 KiB contiguous (plain stores; nt
// regressed in R4).
// ---------------------------------------------------------------------------
__global__ __launch_bounds__(256) void fused_kernel(const float* __restrict__ pm,
                                                    const float* __restrict__ pf,
                                                    const float* __restrict__ wt,
                                                    floatx4* __restrict__ out) {
  __shared__ float th[12];
  const int tid = threadIdx.x;
  const int blk = blockIdx.x;
  const int b = blk / BLOCKS_PER_BATCH; // block-uniform -> scalar

  if (tid < 64) {
    // ===== wave-0-only rigid solve for batch b =====
    const int lane = tid;
    const int base = b * N_;
    const float wA = wt[base + lane], wB = wt[base + lane + 64];
    float fA[3], fB[3], mA[3], mB[3];
#pragma unroll
    for (int c = 0; c < 3; ++c) {
      fA[c] = pf[(base + lane) * 3 + c];
      fB[c] = pf[(base + lane + 64) * 3 + c];
      mA[c] = pm[(base + lane) * 3 + c];
      mB[c] = pm[(base + lane + 64) * 3 + c];
    }

    // centroids: 6 butterfly reductions (result lands in ALL lanes)
    float sums[6];
#pragma unroll
    for (int c = 0; c < 3; ++c) {
      sums[c]     = wA * fA[c] + wB * fB[c];
      sums[3 + c] = wA * mA[c] + wB * mB[c];
    }
#pragma unroll
    for (int k = 0; k < 6; ++k) {
      float v = sums[k];
#pragma unroll
      for (int o = 1; o < 64; o <<= 1) v += __shfl_xor(v, o, 64);
      sums[k] = v;
    }

    // cross-covariance H: 9 butterfly reductions
    float q1A[3], q1B[3], q2A[3], q2B[3];
#pragma unroll
    for (int c = 0; c < 3; ++c) {
      q1A[c] = (fA[c] - sums[c]) * wA;     q1B[c] = (fB[c] - sums[c]) * wB;
      q2A[c] = (mA[c] - sums[3 + c]) * wA; q2B[c] = (mB[c] - sums[3 + c]) * wB;
    }
    float X[3][3];
#pragma unroll
    for (int i = 0; i < 3; ++i)
#pragma unroll
      for (int j = 0; j < 3; ++j)
        X[i][j] = q1A[i] * q2A[j] + q1B[i] * q2B[j];
#pragma unroll
    for (int i = 0; i < 3; ++i)
#pragma unroll
      for (int j = 0; j < 3; ++j) {
        float v = X[i][j];
#pragma unroll
        for (int o = 1; o < 64; o <<= 1) v += __shfl_xor(v, o, 64);
        X[i][j] = v;
      }

    // polar solve (all 64 lanes redundantly; values wave-uniform)
    {
      float fr = 0.0f;
#pragma unroll
      for (int i = 0; i < 3; ++i)
#pragma unroll
        for (int j = 0; j < 3; ++j) fr = fmaf(X[i][j], X[i][j], fr);
      fr = sqrtf(fr);
      if (fr < 1e-30f) fr = 1.0f;
      const float ifr = 1.0f / fr;
#pragma unroll
      for (int i = 0; i < 3; ++i)
#pragma unroll
        for (int j = 0; j < 3; ++j) X[i][j] *= ifr;
    }

    for (int it = 0; it < 8; ++it) {
      float C[3][3];
      C[0][0] =  X[1][1] * X[2][2] - X[1][2] * X[2][1];
      C[0][1] = -(X[1][0] * X[2][2] - X[1][2] * X[2][0]);
      C[0][2] =  X[1][0] * X[2][1] - X[1][1] * X[2][0];
      C[1][0] = -(X[0][1] * X[2][2] - X[0][2] * X[2][1]);
      C[1][1] =  X[0][0] * X[2][2] - X[0][2] * X[2][0];
      C[1][2] = -(X[0][0] * X[2][1] - X[0][1] * X[2][0]);
      C[2][0] =  X[0][1] * X[1][2] - X[0][2] * X[1][1];
      C[2][1] = -(X[0][0] * X[1][2] - X[0][2] * X[1][0]);
      C[2][2] =  X[0][0] * X[1][1] - X[0][1] * X[1][0];
      float det = X[0][0] * C[0][0] + X[0][1] * C[0][1] + X[0][2] * C[0][2];
      // mu ~= |det|^(-1/3): precision affects only convergence rate.
      float ad = fabsf(det);
      float mu = (ad > 1e-30f && ad < 1e30f)
                     ? exp2f(log2f(ad) * (-1.0f / 3.0f)) : 1.0f;
      float inv = 1.0f / (mu * det);
#pragma unroll
      for (int i = 0; i < 3; ++i)
#pragma unroll
        for (int j = 0; j < 3; ++j)
          X[i][j] = 0.5f * fmaf(mu, X[i][j], C[i][j] * inv);
    }

    // R_init = X^T; flip 3rd row by sign(det); T = c2 - R c1
    float R[3][3];
#pragma unroll
    for (int i = 0; i < 3; ++i)
#pragma unroll
      for (int j = 0; j < 3; ++j) R[i][j] = X[j][i];
    {
      float det = R[0][0] * (R[1][1] * R[2][2] - R[1][2] * R[2][1])
                - R[0][1] * (R[1][0] * R[2][2] - R[1][2] * R[2][0])
                + R[0][2] * (R[1][0] * R[2][1] - R[1][1] * R[2][0]);
      float s = (det < 0.0f) ? -1.0f : 1.0f;
      R[2][0] *= s; R[2][1] *= s; R[2][2] *= s;
    }
    if (lane == 0) {
      th[0] = R[0][0]; th[1] = R[0][1]; th[2]  = R[0][2];
      th[3] = sums[3] - (R[0][0]*sums[0] + R[0][1]*sums[1] + R[0][2]*sums[2]);
      th[4] = R[1][0]; th[5] = R[1][1]; th[6]  = R[1][2];
      th[7] = sums[4] - (R[1][0]*sums[0] + R[1][1]*sums[1] + R[1][2]*sums[2]);
      th[8] = R[2][0]; th[9] = R[2][1]; th[10] = R[2][2];
      th[11] = sums[5] - (R[2][0]*sums[0] + R[2][1]*sums[1] + R[2][2]*sums[2]);
    }
  }
  __syncthreads();

  // broadcast theta from LDS (same-address reads: conflict-free)
  const float r00 = th[0], r01 = th[1], r02 = th[2],  t0 = th[3];
  const float r10 = th[4], r11 = th[5], r12 = th[6],  t1 = th[7];
  const float r20 = th[8], r21 = th[9], r22 = th[10], t2 = th[11];
  const float dx = 2.0f / (float)W_;

  // ===== write-streaming: 25 float4s per thread, stride 256 =====
  int f = blk * F4_PER_BLOCK + tid;
#pragma unroll 5
  for (int k = 0; k < 25; ++k, f += 256) {
    const int row = f / F_PER_ROW;
    const int lf4 = f - row * F_PER_ROW;
    const int h = row % H_;
    const int d = (row / H_) % D_;

    const int lf = lf4 * 4;        // float offset within row, 0..476
    const int w0 = lf / 3;         // first voxel covered
    const int phase = lf - 3 * w0; // 0,1,2

    const float y = (2.0f * (float)h + 1.0f) * (1.0f / (float)H_) - 1.0f;
    const float z = (2.0f * (float)d + 1.0f) * (1.0f / (float)D_) - 1.0f;
    const float x0 = (2.0f * (float)w0 + 1.0f) * (1.0f / (float)W_) - 1.0f;

    const float A0 = fmaf(r00, x0, fmaf(r01, y, fmaf(r02, z, t0)));
    const float A1 = fmaf(r10, x0, fmaf(r11, y, fmaf(r12, z, t1)));
    const float A2 = fmaf(r20, x0, fmaf(r21, y, fmaf(r22, z, t2)));
    const float B0 = fmaf(r00, dx, A0);
    const float B1 = fmaf(r10, dx, A1);
    const float B2 = fmaf(r20, dx, A2);

    floatx4 o;
    o.x = (phase == 0) ? A0 : ((phase == 1) ? A1 : A2);
    o.y = (phase == 0) ? A1 : ((phase == 1) ? A2 : B0);
    o.z = (phase == 0) ? A2 : ((phase == 1) ? B0 : B1);
    o.w = (phase == 0) ? B0 : ((phase == 1) ? B1 : B2);

    out[f] = o;
  }
}

extern "C" void kernel_launch(void* const* d_in, const int* in_sizes, int n_in,
                              void* d_out, int out_size, void* d_ws, size_t ws_size,
                              hipStream_t stream) {
  const float* pm = (const float*)d_in[0]; // points_m [B,N,3]
  const float* pf = (const float*)d_in[1]; // points_f [B,N,3]
  const float* wt = (const float*)d_in[2]; // weights  [B,1,N]
  floatx4* out = (floatx4*)d_out;          // [B,D,H,W,3] f32 as float4s

  fused_kernel<<<NBLOCKS, 256, 0, stream>>>(pm, pf, wt, out);
}